// Round 3
// baseline (554.981 us; speedup 1.0000x reference)
//
#include <hip/hip_runtime.h>

// MPM P2G, gather formulation with cell-granular index buckets.
//
// node[g] = sum over particles in the 8 cells {g-1,g}^3 of trilinear w * (m, m*v)
// cell/node id: z + x*128 + y*128*128   (reference get_hash, dim==3)
//
// Pipeline (no sort, no scan, no LDS atomics, no global atomics on the hot path):
//   K1 place : per particle, atomicAdd on its cell counter (lambda~0.5 -> no
//              contention), write particle index into a fixed-capacity slot.
//   K2 gather: one thread per node; loop 8 neighbor cells, register-accumulate,
//              one coalesced float4 store per node. Covers every node -> no memset.
//   K3 fixup : rare capacity-overflow particles scatter with global atomics.

#define GRID_DIM   128
#define NUM_CELLS  (GRID_DIM * GRID_DIM * GRID_DIM)   // 2,097,152
#define INV_CELL   64.0f
#define OVF_MAX    65536

__device__ __forceinline__ int cell_id(int ix, int iy, int iz) {
    return iz + ix * GRID_DIM + iy * (GRID_DIM * GRID_DIM);
}

// ---- K1: bucket placement --------------------------------------------------
__global__ __launch_bounds__(256) void place_kernel(
    const float* __restrict__ pos,
    unsigned int* __restrict__ counts,   // [NUM_CELLS]
    int* __restrict__ idx,               // [NUM_CELLS * cap]
    int* __restrict__ ovf_cnt,           // [1]
    int* __restrict__ ovf_list,          // [OVF_MAX]
    int cap, int n)
{
    int i = blockIdx.x * 256 + threadIdx.x;
    if (i >= n) return;
    int ix = (int)floorf(pos[3 * i + 0] * INV_CELL);
    int iy = (int)floorf(pos[3 * i + 1] * INV_CELL);
    int iz = (int)floorf(pos[3 * i + 2] * INV_CELL);
    ix = min(max(ix, 0), GRID_DIM - 1);
    iy = min(max(iy, 0), GRID_DIM - 1);
    iz = min(max(iz, 0), GRID_DIM - 1);
    int c = cell_id(ix, iy, iz);
    unsigned int s = atomicAdd(&counts[c], 1u);
    if (s < (unsigned int)cap) {
        idx[c * cap + (int)s] = i;
    } else {
        int o = atomicAdd(ovf_cnt, 1);
        if (o < OVF_MAX) ovf_list[o] = i;
    }
}

// ---- K2: node gather -------------------------------------------------------
__global__ __launch_bounds__(256) void node_gather_kernel(
    const float* __restrict__ pos,
    const float* __restrict__ vel,
    const float* __restrict__ mass,
    const unsigned int* __restrict__ counts,
    const int* __restrict__ idx,
    float4* __restrict__ out,            // [NUM_CELLS]
    int cap)
{
    int id = blockIdx.x * 256 + threadIdx.x;   // node id, z-fastest
    int gz = id & (GRID_DIM - 1);
    int gx = (id >> 7) & (GRID_DIM - 1);
    int gy = id >> 14;
    float fgx = (float)gx, fgy = (float)gy, fgz = (float)gz;

    float a0 = 0.0f, a1 = 0.0f, a2 = 0.0f, a3 = 0.0f;

    int y0 = max(gy - 1, 0);
    int x0 = max(gx - 1, 0);
    int z0 = max(gz - 1, 0);

    for (int cy = y0; cy <= gy; ++cy) {
        for (int cx = x0; cx <= gx; ++cx) {
            int cb = cx * GRID_DIM + cy * (GRID_DIM * GRID_DIM);
            for (int cz = z0; cz <= gz; ++cz) {
                int c = cb + cz;
                int cnt = min((int)counts[c], cap);
                int base = c * cap;
                for (int j = 0; j < cnt; ++j) {
                    int p = idx[base + j];
                    float rx = pos[3 * p + 0] * INV_CELL;
                    float ry = pos[3 * p + 1] * INV_CELL;
                    float rz = pos[3 * p + 2] * INV_CELL;
                    // particle is in cell (cx,cy,cz) adjacent to node -> |d|<1
                    float w = (1.0f - fabsf(rx - fgx)) *
                              (1.0f - fabsf(ry - fgy)) *
                              (1.0f - fabsf(rz - fgz));
                    float sm = w * mass[p];
                    a0 += sm;
                    a1 += sm * vel[3 * p + 0];
                    a2 += sm * vel[3 * p + 1];
                    a3 += sm * vel[3 * p + 2];
                }
            }
        }
    }
    out[id] = make_float4(a0, a1, a2, a3);  // every node written: no memset
}

// ---- K3: overflow fixup (rare) ---------------------------------------------
__global__ __launch_bounds__(256) void fixup_kernel(
    const float* __restrict__ pos, const float* __restrict__ vel,
    const float* __restrict__ mass, const int* __restrict__ ovf_cnt,
    const int* __restrict__ ovf_list, float* __restrict__ out)
{
    int total = min(*ovf_cnt, OVF_MAX);
    for (int k = blockIdx.x * 256 + threadIdx.x; k < total;
         k += gridDim.x * 256) {
        int i = ovf_list[k];
        float px = pos[3 * i + 0] * INV_CELL;
        float py = pos[3 * i + 1] * INV_CELL;
        float pz = pos[3 * i + 2] * INV_CELL;
        float bx = floorf(px), by = floorf(py), bz = floorf(pz);
        float fx = px - bx, fy = py - by, fz = pz - bz;
        int ix = (int)bx, iy = (int)by, iz = (int)bz;
        float m = mass[i];
        float vx = vel[3 * i + 0], vy = vel[3 * i + 1], vz = vel[3 * i + 2];
        float wx[2] = { 1.0f - fx, fx };
        float wy[2] = { 1.0f - fy, fy };
        float wz[2] = { 1.0f - fz, fz };
        #pragma unroll
        for (int a = 0; a < 2; ++a)
            #pragma unroll
            for (int b = 0; b < 2; ++b)
                #pragma unroll
                for (int c = 0; c < 2; ++c) {
                    int h = cell_id(ix + a, iy + b, iz + c);
                    bool valid = (h >= 0) && (h < NUM_CELLS);
                    int hc = min(max(h, 0), NUM_CELLS - 1);
                    float s = valid ? (wx[a] * wy[b] * wz[c]) : 0.0f;
                    float sm = s * m;
                    float* cell = out + 4 * (size_t)hc;
                    atomicAdd(cell + 0, sm);
                    atomicAdd(cell + 1, sm * vx);
                    atomicAdd(cell + 2, sm * vy);
                    atomicAdd(cell + 3, sm * vz);
                }
    }
}

// ---- fallback: verified naive atomic scatter -------------------------------
__global__ __launch_bounds__(256) void p2g_scatter_kernel(
    const float* __restrict__ pos, const float* __restrict__ vel,
    const float* __restrict__ mass, float* __restrict__ out, int n)
{
    int i = blockIdx.x * blockDim.x + threadIdx.x;
    if (i >= n) return;
    float px = pos[3 * i + 0] * INV_CELL;
    float py = pos[3 * i + 1] * INV_CELL;
    float pz = pos[3 * i + 2] * INV_CELL;
    float bx = floorf(px), by = floorf(py), bz = floorf(pz);
    float fx = px - bx, fy = py - by, fz = pz - bz;
    int ix = (int)bx, iy = (int)by, iz = (int)bz;
    float m = mass[i];
    float vx = vel[3 * i + 0], vy = vel[3 * i + 1], vz = vel[3 * i + 2];
    float wx[2] = { 1.0f - fx, fx }, wy[2] = { 1.0f - fy, fy }, wz[2] = { 1.0f - fz, fz };
    #pragma unroll
    for (int a = 0; a < 2; ++a)
        #pragma unroll
        for (int b = 0; b < 2; ++b)
            #pragma unroll
            for (int c = 0; c < 2; ++c) {
                int h = cell_id(ix + a, iy + b, iz + c);
                bool valid = (h >= 0) && (h < NUM_CELLS);
                int hc = min(max(h, 0), NUM_CELLS - 1);
                float s = valid ? (wx[a] * wy[b] * wz[c]) : 0.0f;
                float sm = s * m;
                float* cell = out + 4 * (size_t)hc;
                atomicAdd(cell + 0, sm);
                atomicAdd(cell + 1, sm * vx);
                atomicAdd(cell + 2, sm * vy);
                atomicAdd(cell + 3, sm * vz);
            }
}

extern "C" void kernel_launch(void* const* d_in, const int* in_sizes, int n_in,
                              void* d_out, int out_size, void* d_ws, size_t ws_size,
                              hipStream_t stream) {
    const float* pos  = (const float*)d_in[0];
    const float* vel  = (const float*)d_in[1];
    const float* mass = (const float*)d_in[2];
    float* out = (float*)d_out;
    int n = in_sizes[2];

    // ws layout: [counts 8MB][idx cap*8MB][ovf_cnt 256B][ovf_list 256KB]
    auto need = [](int cap) {
        return (size_t)NUM_CELLS * 4                 // counts
             + (size_t)NUM_CELLS * cap * 4           // idx
             + 256 + (size_t)OVF_MAX * 4;            // ovf
    };

    int cap = 0;
    if (ws_size >= need(4))      cap = 4;
    else if (ws_size >= need(3)) cap = 3;

    if (cap > 0) {
        char* ws = (char*)d_ws;
        unsigned int* counts = (unsigned int*)ws;
        int* idx     = (int*)(ws + (size_t)NUM_CELLS * 4);
        int* ovf_cnt = (int*)(ws + (size_t)NUM_CELLS * 4 + (size_t)NUM_CELLS * cap * 4);
        int* ovf_list = ovf_cnt + 64;

        hipMemsetAsync(counts, 0, (size_t)NUM_CELLS * 4, stream);
        hipMemsetAsync(ovf_cnt, 0, 4, stream);

        int blocks = (n + 255) / 256;
        place_kernel<<<blocks, 256, 0, stream>>>(pos, counts, idx, ovf_cnt,
                                                 ovf_list, cap, n);
        node_gather_kernel<<<NUM_CELLS / 256, 256, 0, stream>>>(
            pos, vel, mass, counts, idx, (float4*)out, cap);
        fixup_kernel<<<32, 256, 0, stream>>>(pos, vel, mass, ovf_cnt,
                                             ovf_list, out);
    } else {
        hipMemsetAsync(out, 0, (size_t)out_size * sizeof(float), stream);
        int block = 256;
        int grid = (n + block - 1) / block;
        p2g_scatter_kernel<<<grid, block, 0, stream>>>(pos, vel, mass, out, n);
    }
}

// Round 4
// 228.058 us; speedup vs baseline: 2.4335x; 2.4335x over previous
//
#include <hip/hip_runtime.h>

// MPM P2G, node-gather over cell-sorted particle records.
//
// node[g] = sum over particles in cells {g-1,g}^3 of trilinear w * (m, m*v)
// cell/node id: z + x*128 + y*128*128   (reference get_hash, dim==3)
//
// Pipeline:
//   K1 hist     : count particles per cell (2M counters, ~0.5/cell)
//   K2a/b/c scan: exclusive scan of counts -> offsets (3-phase, 2048 partials)
//   K3 binplace : scatter 32B records {rel.xyz,m},{vel.xyz,_} into sorted slots
//   K4 gather   : 1 thread/node, 4 contiguous record ranges (z-pairs merge),
//                 register accumulate, one coalesced float4 store. No atomics
//                 on d_out, no memset (every node written).
// After K3, cursors[c] == offsets[c]+count[c] == range end (reused in K4).

#define GRID_DIM   128
#define NUM_CELLS  (GRID_DIM * GRID_DIM * GRID_DIM)   // 2,097,152
#define INV_CELL   64.0f
#define SCAN_BLKS  2048
#define SCAN_CHUNK (NUM_CELLS / SCAN_BLKS)            // 1024 cells per block

__device__ __forceinline__ int cell_id(int ix, int iy, int iz) {
    return iz + ix * GRID_DIM + iy * (GRID_DIM * GRID_DIM);
}

// ---- K1: histogram ---------------------------------------------------------
__global__ __launch_bounds__(256) void hist_kernel(
    const float* __restrict__ pos, int* __restrict__ counts, int n)
{
    int i = blockIdx.x * 256 + threadIdx.x;
    if (i >= n) return;
    int ix = min(max((int)floorf(pos[3 * i + 0] * INV_CELL), 0), GRID_DIM - 1);
    int iy = min(max((int)floorf(pos[3 * i + 1] * INV_CELL), 0), GRID_DIM - 1);
    int iz = min(max((int)floorf(pos[3 * i + 2] * INV_CELL), 0), GRID_DIM - 1);
    atomicAdd(&counts[cell_id(ix, iy, iz)], 1);
}

// ---- K2a: per-block partial sums ------------------------------------------
__global__ __launch_bounds__(256) void scan_partials_kernel(
    const int* __restrict__ counts, int* __restrict__ partials)
{
    __shared__ int red[256];
    int t = threadIdx.x;
    const int4* c4 = (const int4*)counts;
    int4 v = c4[blockIdx.x * 256 + t];
    red[t] = v.x + v.y + v.z + v.w;
    __syncthreads();
    for (int off = 128; off > 0; off >>= 1) {
        if (t < off) red[t] += red[t + off];
        __syncthreads();
    }
    if (t == 0) partials[blockIdx.x] = red[0];
}

// ---- K2b: scan the 2048 partials (single block) ---------------------------
__global__ __launch_bounds__(1024) void scan_tops_kernel(int* __restrict__ partials)
{
    __shared__ int s[1024];
    int t = threadIdx.x;
    int p0 = partials[2 * t], p1 = partials[2 * t + 1];
    int sum = p0 + p1;
    s[t] = sum;
    __syncthreads();
    for (int off = 1; off < 1024; off <<= 1) {
        int x = (t >= off) ? s[t - off] : 0;
        __syncthreads();
        s[t] += x;
        __syncthreads();
    }
    int excl = s[t] - sum;
    partials[2 * t]     = excl;
    partials[2 * t + 1] = excl + p0;
}

// ---- K2c: block-local scan + base -> offsets & cursors --------------------
__global__ __launch_bounds__(256) void scan_final_kernel(
    const int* __restrict__ counts, const int* __restrict__ partials,
    int* __restrict__ offsets, int* __restrict__ cursors)
{
    __shared__ int s[256];
    int t = threadIdx.x;
    int g = blockIdx.x * 256 + t;
    const int4* c4 = (const int4*)counts;
    int4 v = c4[g];
    int sum = v.x + v.y + v.z + v.w;
    s[t] = sum;
    __syncthreads();
    for (int off = 1; off < 256; off <<= 1) {
        int x = (t >= off) ? s[t - off] : 0;
        __syncthreads();
        s[t] += x;
        __syncthreads();
    }
    int run = partials[blockIdx.x] + s[t] - sum;
    int4 o = make_int4(run, run + v.x, run + v.x + v.y, run + v.x + v.y + v.z);
    ((int4*)offsets)[g] = o;
    ((int4*)cursors)[g] = o;
}

// ---- K3: place sorted 32B records -----------------------------------------
__global__ __launch_bounds__(256) void binplace_kernel(
    const float* __restrict__ pos, const float* __restrict__ vel,
    const float* __restrict__ mass, int* __restrict__ cursors,
    float4* __restrict__ records, int n)
{
    int i = blockIdx.x * 256 + threadIdx.x;
    if (i >= n) return;
    float rx = pos[3 * i + 0] * INV_CELL;
    float ry = pos[3 * i + 1] * INV_CELL;
    float rz = pos[3 * i + 2] * INV_CELL;
    int ix = min(max((int)floorf(rx), 0), GRID_DIM - 1);
    int iy = min(max((int)floorf(ry), 0), GRID_DIM - 1);
    int iz = min(max((int)floorf(rz), 0), GRID_DIM - 1);
    int slot = atomicAdd(&cursors[cell_id(ix, iy, iz)], 1);
    records[2 * slot + 0] = make_float4(rx, ry, rz, mass[i]);
    records[2 * slot + 1] = make_float4(vel[3 * i + 0], vel[3 * i + 1],
                                        vel[3 * i + 2], 0.0f);
}

// ---- K4: node gather over sorted ranges -----------------------------------
__global__ __launch_bounds__(256) void node_gather_kernel(
    const float4* __restrict__ records,
    const int* __restrict__ offsets,     // range starts
    const int* __restrict__ cursors,     // post-binplace == range ends
    float4* __restrict__ out)
{
    int id = blockIdx.x * 256 + threadIdx.x;   // node id, z-fastest
    int gz = id & (GRID_DIM - 1);
    int gx = (id >> 7) & (GRID_DIM - 1);
    int gy = id >> 14;
    float fgx = (float)gx, fgy = (float)gy, fgz = (float)gz;

    float a0 = 0.0f, a1 = 0.0f, a2 = 0.0f, a3 = 0.0f;

    int z0 = max(gz - 1, 0);
    int y0 = max(gy - 1, 0);
    int x0 = max(gx - 1, 0);

    for (int cy = y0; cy <= gy; ++cy) {
        for (int cx = x0; cx <= gx; ++cx) {
            int cb = cx * GRID_DIM + cy * (GRID_DIM * GRID_DIM);
            int beg = offsets[cb + z0];
            int end = cursors[cb + gz];
            for (int p = beg; p < end; ++p) {
                float4 r0 = records[2 * p + 0];
                float4 r1 = records[2 * p + 1];
                float w = (1.0f - fabsf(r0.x - fgx)) *
                          (1.0f - fabsf(r0.y - fgy)) *
                          (1.0f - fabsf(r0.z - fgz));
                float sm = w * r0.w;
                a0 += sm;
                a1 += sm * r1.x;
                a2 += sm * r1.y;
                a3 += sm * r1.z;
            }
        }
    }
    out[id] = make_float4(a0, a1, a2, a3);
}

// ======== fallback pipeline (R1, verified 372us): tile-LDS scatter =========
#define TILE   8
#define NTILE  (GRID_DIM / TILE)
#define NBINS  (NTILE * NTILE * NTILE)
#define NCOPY  8
#define NBINSF (NBINS * NCOPY)

__device__ __forceinline__ int bin_of(int ix, int iy, int iz) {
    return ((iy >> 3) * NTILE + (ix >> 3)) * NTILE + (iz >> 3);
}

__global__ __launch_bounds__(256) void f_hist_kernel(
    const float* __restrict__ pos, int* __restrict__ countsF, int n)
{
    int i = blockIdx.x * 256 + threadIdx.x;
    if (i >= n) return;
    int ix = min(max((int)floorf(pos[3 * i + 0] * INV_CELL), 0), GRID_DIM - 1);
    int iy = min(max((int)floorf(pos[3 * i + 1] * INV_CELL), 0), GRID_DIM - 1);
    int iz = min(max((int)floorf(pos[3 * i + 2] * INV_CELL), 0), GRID_DIM - 1);
    atomicAdd(&countsF[bin_of(ix, iy, iz) * NCOPY + (threadIdx.x & (NCOPY - 1))], 1);
}

__global__ __launch_bounds__(1024) void f_scan_kernel(
    const int* __restrict__ countsF, int* __restrict__ offsetsF,
    int* __restrict__ cursorsF)
{
    __shared__ int sums[1024];
    const int ITEMS = NBINSF / 1024;
    int t = threadIdx.x;
    int base = t * ITEMS;
    int v[ITEMS];
    int s = 0;
    #pragma unroll
    for (int j = 0; j < ITEMS; ++j) { v[j] = countsF[base + j]; s += v[j]; }
    sums[t] = s;
    __syncthreads();
    for (int off = 1; off < 1024; off <<= 1) {
        int x = (t >= off) ? sums[t - off] : 0;
        __syncthreads();
        sums[t] += x;
        __syncthreads();
    }
    int run = sums[t] - s;
    #pragma unroll
    for (int j = 0; j < ITEMS; ++j) {
        offsetsF[base + j] = run;
        cursorsF[base + j] = run;
        run += v[j];
    }
    if (t == 1023) offsetsF[NBINSF] = run;
}

__global__ __launch_bounds__(256) void f_binplace_kernel(
    const float* __restrict__ pos, const float* __restrict__ vel,
    const float* __restrict__ mass, int* __restrict__ cursorsF,
    float4* __restrict__ records, int n)
{
    int i = blockIdx.x * 256 + threadIdx.x;
    if (i >= n) return;
    float px = pos[3 * i + 0] * INV_CELL;
    float py = pos[3 * i + 1] * INV_CELL;
    float pz = pos[3 * i + 2] * INV_CELL;
    float bx = floorf(px), by = floorf(py), bz = floorf(pz);
    int ix = min(max((int)bx, 0), GRID_DIM - 1);
    int iy = min(max((int)by, 0), GRID_DIM - 1);
    int iz = min(max((int)bz, 0), GRID_DIM - 1);
    int bf = bin_of(ix, iy, iz) * NCOPY + (threadIdx.x & (NCOPY - 1));
    int slot = atomicAdd(&cursorsF[bf], 1);
    int packed = ix | (iy << 7) | (iz << 14);
    records[2 * slot + 0] = make_float4(__int_as_float(packed),
                                        px - bx, py - by, pz - bz);
    records[2 * slot + 1] = make_float4(mass[i], vel[3 * i + 0],
                                        vel[3 * i + 1], vel[3 * i + 2]);
}

__global__ __launch_bounds__(256) void f_gather_kernel(
    const float4* __restrict__ records, const int* __restrict__ offsetsF,
    float4* __restrict__ out)
{
    __shared__ float acc[TILE * TILE * TILE * 4];
    int tid = threadIdx.x;
    int b = blockIdx.x;
    int tz = b & (NTILE - 1);
    int tx = (b >> 4) & (NTILE - 1);
    int ty = b >> 8;
    int ox = tx * TILE, oy = ty * TILE, oz = tz * TILE;
    for (int j = tid; j < TILE * TILE * TILE * 4; j += 256) acc[j] = 0.0f;
    __syncthreads();
    for (int dy = -1; dy <= 0; ++dy) {
        int sy = ty + dy; if (sy < 0) continue;
        for (int dx = -1; dx <= 0; ++dx) {
            int sx = tx + dx; if (sx < 0) continue;
            int z0 = (tz > 0) ? tz - 1 : 0;
            int s0 = (sy * NTILE + sx) * NTILE + z0;
            int s1 = (sy * NTILE + sx) * NTILE + tz;
            int beg = offsetsF[s0 * NCOPY];
            int end = offsetsF[s1 * NCOPY + NCOPY];
            for (int p = beg + tid; p < end; p += 256) {
                float4 r0 = records[2 * p + 0];
                float4 r1 = records[2 * p + 1];
                int packed = __float_as_int(r0.x);
                int ix = packed & 127;
                int iy = (packed >> 7) & 127;
                int iz = (packed >> 14) & 127;
                float fx = r0.y, fy = r0.z, fz = r0.w;
                float m = r1.x, vx = r1.y, vy = r1.z, vz = r1.w;
                int lx0 = ix - ox, ly0 = iy - oy, lz0 = iz - oz;
                float wxm[2] = { (1.0f - fx) * m, fx * m };
                float wy[2]  = { 1.0f - fy, fy };
                float wz[2]  = { 1.0f - fz, fz };
                #pragma unroll
                for (int a = 0; a < 2; ++a)
                    #pragma unroll
                    for (int b2 = 0; b2 < 2; ++b2)
                        #pragma unroll
                        for (int c = 0; c < 2; ++c) {
                            int lx = lx0 + a, ly = ly0 + b2, lz = lz0 + c;
                            if ((unsigned)lx < (unsigned)TILE &&
                                (unsigned)ly < (unsigned)TILE &&
                                (unsigned)lz < (unsigned)TILE) {
                                float sm = wxm[a] * wy[b2] * wz[c];
                                int idx = (((ly * TILE + lx) * TILE) + lz) * 4;
                                atomicAdd(&acc[idx + 0], sm);
                                atomicAdd(&acc[idx + 1], sm * vx);
                                atomicAdd(&acc[idx + 2], sm * vy);
                                atomicAdd(&acc[idx + 3], sm * vz);
                            }
                        }
            }
        }
    }
    __syncthreads();
    for (int c = tid; c < TILE * TILE * TILE; c += 256) {
        int lz = c & 7, lx = (c >> 3) & 7, ly = c >> 6;
        float4 val = *(const float4*)&acc[c * 4];
        out[(oz + lz) + (ox + lx) * GRID_DIM + (oy + ly) * (GRID_DIM * GRID_DIM)] = val;
    }
}

// ---- last-resort naive scatter --------------------------------------------
__global__ __launch_bounds__(256) void p2g_scatter_kernel(
    const float* __restrict__ pos, const float* __restrict__ vel,
    const float* __restrict__ mass, float* __restrict__ out, int n)
{
    int i = blockIdx.x * blockDim.x + threadIdx.x;
    if (i >= n) return;
    float px = pos[3 * i + 0] * INV_CELL;
    float py = pos[3 * i + 1] * INV_CELL;
    float pz = pos[3 * i + 2] * INV_CELL;
    float bx = floorf(px), by = floorf(py), bz = floorf(pz);
    float fx = px - bx, fy = py - by, fz = pz - bz;
    int ix = (int)bx, iy = (int)by, iz = (int)bz;
    float m = mass[i];
    float vx = vel[3 * i + 0], vy = vel[3 * i + 1], vz = vel[3 * i + 2];
    float wx[2] = { 1.0f - fx, fx }, wy[2] = { 1.0f - fy, fy }, wz[2] = { 1.0f - fz, fz };
    #pragma unroll
    for (int a = 0; a < 2; ++a)
        #pragma unroll
        for (int b = 0; b < 2; ++b)
            #pragma unroll
            for (int c = 0; c < 2; ++c) {
                int h = cell_id(ix + a, iy + b, iz + c);
                bool valid = (h >= 0) && (h < NUM_CELLS);
                int hc = min(max(h, 0), NUM_CELLS - 1);
                float s = valid ? (wx[a] * wy[b] * wz[c]) : 0.0f;
                float sm = s * m;
                float* cell = out + 4 * (size_t)hc;
                atomicAdd(cell + 0, sm);
                atomicAdd(cell + 1, sm * vx);
                atomicAdd(cell + 2, sm * vy);
                atomicAdd(cell + 3, sm * vz);
            }
}

extern "C" void kernel_launch(void* const* d_in, const int* in_sizes, int n_in,
                              void* d_out, int out_size, void* d_ws, size_t ws_size,
                              hipStream_t stream) {
    const float* pos  = (const float*)d_in[0];
    const float* vel  = (const float*)d_in[1];
    const float* mass = (const float*)d_in[2];
    float* out = (float*)d_out;
    int n = in_sizes[2];

    // Main path ws: [counts/cursors 8MB][offsets 8MB][records n*32][partials 8KB]
    size_t off_offsets  = (size_t)NUM_CELLS * 4;
    size_t off_records  = off_offsets + (size_t)NUM_CELLS * 4;
    size_t off_partials = off_records + (size_t)n * 32;
    size_t need_main    = off_partials + (size_t)SCAN_BLKS * 4;

    // Fallback (R1) ws: [records n*32][countsF][offsetsF+1][cursorsF]
    size_t f_off_counts  = (size_t)n * 32;
    size_t f_off_offsets = f_off_counts + (size_t)NBINSF * 4;
    size_t f_off_cursors = f_off_offsets + (size_t)(NBINSF + 1) * 4;
    size_t need_fallback = f_off_cursors + (size_t)NBINSF * 4;

    int blocks = (n + 255) / 256;

    if (ws_size >= need_main) {
        char* ws = (char*)d_ws;
        int* counts   = (int*)ws;                    // reused as cursors
        int* offsets  = (int*)(ws + off_offsets);
        float4* records = (float4*)(ws + off_records);
        int* partials = (int*)(ws + off_partials);

        hipMemsetAsync(counts, 0, (size_t)NUM_CELLS * 4, stream);
        hist_kernel<<<blocks, 256, 0, stream>>>(pos, counts, n);
        scan_partials_kernel<<<SCAN_BLKS, 256, 0, stream>>>(counts, partials);
        scan_tops_kernel<<<1, 1024, 0, stream>>>(partials);
        scan_final_kernel<<<SCAN_BLKS, 256, 0, stream>>>(counts, partials,
                                                         offsets, counts);
        binplace_kernel<<<blocks, 256, 0, stream>>>(pos, vel, mass, counts,
                                                    records, n);
        node_gather_kernel<<<NUM_CELLS / 256, 256, 0, stream>>>(
            records, offsets, counts, (float4*)out);
    } else if (ws_size >= need_fallback) {
        char* ws = (char*)d_ws;
        float4* records = (float4*)ws;
        int* countsF  = (int*)(ws + f_off_counts);
        int* offsetsF = (int*)(ws + f_off_offsets);
        int* cursorsF = (int*)(ws + f_off_cursors);

        hipMemsetAsync(countsF, 0, (size_t)NBINSF * 4, stream);
        f_hist_kernel<<<blocks, 256, 0, stream>>>(pos, countsF, n);
        f_scan_kernel<<<1, 1024, 0, stream>>>(countsF, offsetsF, cursorsF);
        f_binplace_kernel<<<blocks, 256, 0, stream>>>(pos, vel, mass, cursorsF,
                                                      records, n);
        f_gather_kernel<<<NBINS, 256, 0, stream>>>(records, offsetsF,
                                                   (float4*)out);
    } else {
        hipMemsetAsync(out, 0, (size_t)out_size * sizeof(float), stream);
        p2g_scatter_kernel<<<blocks, 256, 0, stream>>>(pos, vel, mass, out, n);
    }
}

// Round 5
// 205.765 us; speedup vs baseline: 2.6972x; 1.1083x over previous
//
#include <hip/hip_runtime.h>
#include <hip/hip_fp16.h>

// MPM P2G, fixed-capacity cell buckets with 16B quantized records.
//
// node[g] = sum over particles in cells {g-1,g}^3 of trilinear w * (m, m*v)
// cell/node id: z + x*128 + y*128*128   (reference get_hash, dim==3)
//
// Primary pipeline (ONE atomic pass, no hist, no scan):
//   K1 place : atomicAdd(cursor[cell]) -> slot; write 16B record
//              {fx,fy,fz as u16 fixed-point, m,vx,vy,vz as fp16}.
//              CAP=4 -> 64B bucket = one cache line per cell.
//   K2 gather: 1 thread/node, <=8 neighbor cells, skip empty (62%),
//              register accumulate, one coalesced float4 store.
//   K3 fixup : rare overflow particles (E ~ 300) exact fp32 atomic scatter.
// Fallback: R3 counting-sort pipeline (verified, needs 48MB), then naive.

#define GRID_DIM   128
#define NUM_CELLS  (GRID_DIM * GRID_DIM * GRID_DIM)   // 2,097,152
#define INV_CELL   64.0f
#define OVF_MAX    65536
#define SCAN_BLKS  2048

__device__ __forceinline__ int cell_id(int ix, int iy, int iz) {
    return iz + ix * GRID_DIM + iy * (GRID_DIM * GRID_DIM);
}

__device__ __forceinline__ unsigned int q16(float f) {
    int q = (int)(f * 65536.0f + 0.5f);
    return (unsigned int)min(q, 65535);
}
__device__ __forceinline__ unsigned int f2h(float f) {
    return (unsigned int)__half_as_ushort(__float2half(f));
}
__device__ __forceinline__ float h2f(unsigned int b) {
    return __half2float(__ushort_as_half((unsigned short)(b & 0xffffu)));
}

// ---- K1: bucket placement (single atomic pass) ----------------------------
__global__ __launch_bounds__(256) void bucket_place_kernel(
    const float* __restrict__ pos, const float* __restrict__ vel,
    const float* __restrict__ mass, unsigned int* __restrict__ cursors,
    uint4* __restrict__ buckets, int* __restrict__ ovf_cnt,
    int* __restrict__ ovf_list, int cap, int n)
{
    int i = blockIdx.x * 256 + threadIdx.x;
    if (i >= n) return;
    float rx = pos[3 * i + 0] * INV_CELL;
    float ry = pos[3 * i + 1] * INV_CELL;
    float rz = pos[3 * i + 2] * INV_CELL;
    float bx = floorf(rx), by = floorf(ry), bz = floorf(rz);
    float fx = rx - bx, fy = ry - by, fz = rz - bz;   // in [0,1)
    int ix = min(max((int)bx, 0), GRID_DIM - 1);
    int iy = min(max((int)by, 0), GRID_DIM - 1);
    int iz = min(max((int)bz, 0), GRID_DIM - 1);
    int c = cell_id(ix, iy, iz);
    unsigned int s = atomicAdd(&cursors[c], 1u);
    if (s < (unsigned int)cap) {
        uint4 r;
        r.x = q16(fx) | (q16(fy) << 16);
        r.y = q16(fz) | (f2h(mass[i]) << 16);
        r.z = f2h(vel[3 * i + 0]) | (f2h(vel[3 * i + 1]) << 16);
        r.w = f2h(vel[3 * i + 2]);
        buckets[c * cap + (int)s] = r;
    } else {
        int o = atomicAdd(ovf_cnt, 1);
        if (o < OVF_MAX) ovf_list[o] = i;
    }
}

// ---- K2: node gather over buckets -----------------------------------------
__global__ __launch_bounds__(256) void bucket_gather_kernel(
    const uint4* __restrict__ buckets, const unsigned int* __restrict__ cursors,
    float4* __restrict__ out, int cap)
{
    int id = blockIdx.x * 256 + threadIdx.x;   // node id, z-fastest
    int gz = id & (GRID_DIM - 1);
    int gx = (id >> 7) & (GRID_DIM - 1);
    int gy = id >> 14;

    float a0 = 0.0f, a1 = 0.0f, a2 = 0.0f, a3 = 0.0f;
    int z0 = max(gz - 1, 0), y0 = max(gy - 1, 0), x0 = max(gx - 1, 0);

    for (int cy = y0; cy <= gy; ++cy) {
        for (int cx = x0; cx <= gx; ++cx) {
            int cb = cx * GRID_DIM + cy * (GRID_DIM * GRID_DIM);
            for (int cz = z0; cz <= gz; ++cz) {
                int c = cb + cz;
                int cnt = (int)cursors[c];
                if (cnt == 0) continue;
                cnt = min(cnt, cap);
                int base = c * cap;
                for (int j = 0; j < cnt; ++j) {
                    uint4 r = buckets[base + j];
                    float fx = (float)(r.x & 0xffffu) * (1.0f / 65536.0f);
                    float fy = (float)(r.x >> 16)     * (1.0f / 65536.0f);
                    float fz = (float)(r.y & 0xffffu) * (1.0f / 65536.0f);
                    // node offset within cell: 0 -> (1-frac), 1 -> frac
                    float wx = (cx == gx) ? (1.0f - fx) : fx;
                    float wy = (cy == gy) ? (1.0f - fy) : fy;
                    float wz = (cz == gz) ? (1.0f - fz) : fz;
                    float sm = wx * wy * wz * h2f(r.y >> 16);
                    a0 += sm;
                    a1 += sm * h2f(r.z);
                    a2 += sm * h2f(r.z >> 16);
                    a3 += sm * h2f(r.w);
                }
            }
        }
    }
    out[id] = make_float4(a0, a1, a2, a3);   // every node written: no memset
}

// ---- K3: overflow fixup (exact fp32, rare) --------------------------------
__global__ __launch_bounds__(256) void fixup_kernel(
    const float* __restrict__ pos, const float* __restrict__ vel,
    const float* __restrict__ mass, const int* __restrict__ ovf_cnt,
    const int* __restrict__ ovf_list, float* __restrict__ out)
{
    int total = min(*ovf_cnt, OVF_MAX);
    for (int k = blockIdx.x * 256 + threadIdx.x; k < total; k += gridDim.x * 256) {
        int i = ovf_list[k];
        float px = pos[3 * i + 0] * INV_CELL;
        float py = pos[3 * i + 1] * INV_CELL;
        float pz = pos[3 * i + 2] * INV_CELL;
        float bx = floorf(px), by = floorf(py), bz = floorf(pz);
        float fx = px - bx, fy = py - by, fz = pz - bz;
        int ix = (int)bx, iy = (int)by, iz = (int)bz;
        float m = mass[i];
        float vx = vel[3 * i + 0], vy = vel[3 * i + 1], vz = vel[3 * i + 2];
        float wx[2] = { 1.0f - fx, fx }, wy[2] = { 1.0f - fy, fy }, wz[2] = { 1.0f - fz, fz };
        #pragma unroll
        for (int a = 0; a < 2; ++a)
            #pragma unroll
            for (int b = 0; b < 2; ++b)
                #pragma unroll
                for (int c = 0; c < 2; ++c) {
                    int h = cell_id(ix + a, iy + b, iz + c);
                    bool valid = (h >= 0) && (h < NUM_CELLS);
                    int hc = min(max(h, 0), NUM_CELLS - 1);
                    float s = valid ? (wx[a] * wy[b] * wz[c]) : 0.0f;
                    float sm = s * m;
                    float* cell = out + 4 * (size_t)hc;
                    atomicAdd(cell + 0, sm);
                    atomicAdd(cell + 1, sm * vx);
                    atomicAdd(cell + 2, sm * vy);
                    atomicAdd(cell + 3, sm * vz);
                }
    }
}

// ======== fallback: R3 counting-sort pipeline (verified 228us) =============
__global__ __launch_bounds__(256) void s_hist_kernel(
    const float* __restrict__ pos, int* __restrict__ counts, int n)
{
    int i = blockIdx.x * 256 + threadIdx.x;
    if (i >= n) return;
    int ix = min(max((int)floorf(pos[3 * i + 0] * INV_CELL), 0), GRID_DIM - 1);
    int iy = min(max((int)floorf(pos[3 * i + 1] * INV_CELL), 0), GRID_DIM - 1);
    int iz = min(max((int)floorf(pos[3 * i + 2] * INV_CELL), 0), GRID_DIM - 1);
    atomicAdd(&counts[cell_id(ix, iy, iz)], 1);
}

__global__ __launch_bounds__(256) void s_scan_partials_kernel(
    const int* __restrict__ counts, int* __restrict__ partials)
{
    __shared__ int red[256];
    int t = threadIdx.x;
    int4 v = ((const int4*)counts)[blockIdx.x * 256 + t];
    red[t] = v.x + v.y + v.z + v.w;
    __syncthreads();
    for (int off = 128; off > 0; off >>= 1) {
        if (t < off) red[t] += red[t + off];
        __syncthreads();
    }
    if (t == 0) partials[blockIdx.x] = red[0];
}

__global__ __launch_bounds__(1024) void s_scan_tops_kernel(int* __restrict__ partials)
{
    __shared__ int s[1024];
    int t = threadIdx.x;
    int p0 = partials[2 * t], p1 = partials[2 * t + 1];
    int sum = p0 + p1;
    s[t] = sum;
    __syncthreads();
    for (int off = 1; off < 1024; off <<= 1) {
        int x = (t >= off) ? s[t - off] : 0;
        __syncthreads();
        s[t] += x;
        __syncthreads();
    }
    int excl = s[t] - sum;
    partials[2 * t] = excl;
    partials[2 * t + 1] = excl + p0;
}

__global__ __launch_bounds__(256) void s_scan_final_kernel(
    const int* __restrict__ counts, const int* __restrict__ partials,
    int* __restrict__ offsets, int* __restrict__ cursors)
{
    __shared__ int s[256];
    int t = threadIdx.x;
    int g = blockIdx.x * 256 + t;
    int4 v = ((const int4*)counts)[g];
    int sum = v.x + v.y + v.z + v.w;
    s[t] = sum;
    __syncthreads();
    for (int off = 1; off < 256; off <<= 1) {
        int x = (t >= off) ? s[t - off] : 0;
        __syncthreads();
        s[t] += x;
        __syncthreads();
    }
    int run = partials[blockIdx.x] + s[t] - sum;
    int4 o = make_int4(run, run + v.x, run + v.x + v.y, run + v.x + v.y + v.z);
    ((int4*)offsets)[g] = o;
    ((int4*)cursors)[g] = o;
}

__global__ __launch_bounds__(256) void s_binplace_kernel(
    const float* __restrict__ pos, const float* __restrict__ vel,
    const float* __restrict__ mass, int* __restrict__ cursors,
    float4* __restrict__ records, int n)
{
    int i = blockIdx.x * 256 + threadIdx.x;
    if (i >= n) return;
    float rx = pos[3 * i + 0] * INV_CELL;
    float ry = pos[3 * i + 1] * INV_CELL;
    float rz = pos[3 * i + 2] * INV_CELL;
    int ix = min(max((int)floorf(rx), 0), GRID_DIM - 1);
    int iy = min(max((int)floorf(ry), 0), GRID_DIM - 1);
    int iz = min(max((int)floorf(rz), 0), GRID_DIM - 1);
    int slot = atomicAdd(&cursors[cell_id(ix, iy, iz)], 1);
    records[2 * slot + 0] = make_float4(rx, ry, rz, mass[i]);
    records[2 * slot + 1] = make_float4(vel[3 * i + 0], vel[3 * i + 1],
                                        vel[3 * i + 2], 0.0f);
}

__global__ __launch_bounds__(256) void s_node_gather_kernel(
    const float4* __restrict__ records, const int* __restrict__ offsets,
    const int* __restrict__ cursors, float4* __restrict__ out)
{
    int id = blockIdx.x * 256 + threadIdx.x;
    int gz = id & (GRID_DIM - 1);
    int gx = (id >> 7) & (GRID_DIM - 1);
    int gy = id >> 14;
    float fgx = (float)gx, fgy = (float)gy, fgz = (float)gz;
    float a0 = 0.0f, a1 = 0.0f, a2 = 0.0f, a3 = 0.0f;
    int z0 = max(gz - 1, 0), y0 = max(gy - 1, 0), x0 = max(gx - 1, 0);
    for (int cy = y0; cy <= gy; ++cy) {
        for (int cx = x0; cx <= gx; ++cx) {
            int cb = cx * GRID_DIM + cy * (GRID_DIM * GRID_DIM);
            int beg = offsets[cb + z0];
            int end = cursors[cb + gz];
            for (int p = beg; p < end; ++p) {
                float4 r0 = records[2 * p + 0];
                float4 r1 = records[2 * p + 1];
                float w = (1.0f - fabsf(r0.x - fgx)) *
                          (1.0f - fabsf(r0.y - fgy)) *
                          (1.0f - fabsf(r0.z - fgz));
                float sm = w * r0.w;
                a0 += sm; a1 += sm * r1.x; a2 += sm * r1.y; a3 += sm * r1.z;
            }
        }
    }
    out[id] = make_float4(a0, a1, a2, a3);
}

// ---- last-resort naive scatter --------------------------------------------
__global__ __launch_bounds__(256) void p2g_scatter_kernel(
    const float* __restrict__ pos, const float* __restrict__ vel,
    const float* __restrict__ mass, float* __restrict__ out, int n)
{
    int i = blockIdx.x * blockDim.x + threadIdx.x;
    if (i >= n) return;
    float px = pos[3 * i + 0] * INV_CELL;
    float py = pos[3 * i + 1] * INV_CELL;
    float pz = pos[3 * i + 2] * INV_CELL;
    float bx = floorf(px), by = floorf(py), bz = floorf(pz);
    float fx = px - bx, fy = py - by, fz = pz - bz;
    int ix = (int)bx, iy = (int)by, iz = (int)bz;
    float m = mass[i];
    float vx = vel[3 * i + 0], vy = vel[3 * i + 1], vz = vel[3 * i + 2];
    float wx[2] = { 1.0f - fx, fx }, wy[2] = { 1.0f - fy, fy }, wz[2] = { 1.0f - fz, fz };
    #pragma unroll
    for (int a = 0; a < 2; ++a)
        #pragma unroll
        for (int b = 0; b < 2; ++b)
            #pragma unroll
            for (int c = 0; c < 2; ++c) {
                int h = cell_id(ix + a, iy + b, iz + c);
                bool valid = (h >= 0) && (h < NUM_CELLS);
                int hc = min(max(h, 0), NUM_CELLS - 1);
                float s = valid ? (wx[a] * wy[b] * wz[c]) : 0.0f;
                float sm = s * m;
                float* cell = out + 4 * (size_t)hc;
                atomicAdd(cell + 0, sm);
                atomicAdd(cell + 1, sm * vx);
                atomicAdd(cell + 2, sm * vy);
                atomicAdd(cell + 3, sm * vz);
            }
}

extern "C" void kernel_launch(void* const* d_in, const int* in_sizes, int n_in,
                              void* d_out, int out_size, void* d_ws, size_t ws_size,
                              hipStream_t stream) {
    const float* pos  = (const float*)d_in[0];
    const float* vel  = (const float*)d_in[1];
    const float* mass = (const float*)d_in[2];
    float* out = (float*)d_out;
    int n = in_sizes[2];
    int blocks = (n + 255) / 256;

    // Bucket-path ws: [cursors 8MB][buckets cap*16B*2M][ovf_cnt 256B][ovf_list]
    auto bucket_need = [](int cap) {
        return (size_t)NUM_CELLS * 4 + (size_t)NUM_CELLS * cap * 16
             + 256 + (size_t)OVF_MAX * 4;
    };
    int cap = 0;
    if (ws_size >= bucket_need(4))      cap = 4;
    else if (ws_size >= bucket_need(3)) cap = 3;

    // Sorted-path ws: [counts/cursors 8MB][offsets 8MB][records n*32][partials]
    size_t s_off_offsets  = (size_t)NUM_CELLS * 4;
    size_t s_off_records  = s_off_offsets + (size_t)NUM_CELLS * 4;
    size_t s_off_partials = s_off_records + (size_t)n * 32;
    size_t need_sorted    = s_off_partials + (size_t)SCAN_BLKS * 4;

    if (cap > 0) {
        char* ws = (char*)d_ws;
        unsigned int* cursors = (unsigned int*)ws;
        uint4* buckets = (uint4*)(ws + (size_t)NUM_CELLS * 4);
        int* ovf_cnt   = (int*)(ws + (size_t)NUM_CELLS * 4
                                   + (size_t)NUM_CELLS * cap * 16);
        int* ovf_list  = ovf_cnt + 64;

        hipMemsetAsync(cursors, 0, (size_t)NUM_CELLS * 4, stream);
        hipMemsetAsync(ovf_cnt, 0, 4, stream);
        bucket_place_kernel<<<blocks, 256, 0, stream>>>(
            pos, vel, mass, cursors, buckets, ovf_cnt, ovf_list, cap, n);
        bucket_gather_kernel<<<NUM_CELLS / 256, 256, 0, stream>>>(
            buckets, cursors, (float4*)out, cap);
        fixup_kernel<<<32, 256, 0, stream>>>(pos, vel, mass, ovf_cnt,
                                             ovf_list, out);
    } else if (ws_size >= need_sorted) {
        char* ws = (char*)d_ws;
        int* counts   = (int*)ws;                    // reused as cursors
        int* offsets  = (int*)(ws + s_off_offsets);
        float4* records = (float4*)(ws + s_off_records);
        int* partials = (int*)(ws + s_off_partials);

        hipMemsetAsync(counts, 0, (size_t)NUM_CELLS * 4, stream);
        s_hist_kernel<<<blocks, 256, 0, stream>>>(pos, counts, n);
        s_scan_partials_kernel<<<SCAN_BLKS, 256, 0, stream>>>(counts, partials);
        s_scan_tops_kernel<<<1, 1024, 0, stream>>>(partials);
        s_scan_final_kernel<<<SCAN_BLKS, 256, 0, stream>>>(counts, partials,
                                                           offsets, counts);
        s_binplace_kernel<<<blocks, 256, 0, stream>>>(pos, vel, mass, counts,
                                                      records, n);
        s_node_gather_kernel<<<NUM_CELLS / 256, 256, 0, stream>>>(
            records, offsets, counts, (float4*)out);
    } else {
        hipMemsetAsync(out, 0, (size_t)out_size * sizeof(float), stream);
        p2g_scatter_kernel<<<blocks, 256, 0, stream>>>(pos, vel, mass, out, n);
    }
}